// Round 5
// baseline (152.159 us; speedup 1.0000x reference)
//
#include <hip/hip_runtime.h>
#include <hip/hip_bf16.h>

// RadarSecondStageGenerator — MFMA fp16, round 14: kernel fission to break
// phase lockstep. r10/r12/r13 (three different tilings/stagings) all pinned
// at 40.5-42.4us with every pipe <40% busy: 5 barrier phases with disjoint
// pipe usage, all co-resident blocks in lockstep -> no cross-phase overlap.
// Split: K1 = conv_in GEMM -> x image (f16, channel-last, ws+64KB, 8.4MB);
//        K2 = i2h GEMM reading A-frags DIRECT from global x (no staging LDS,
//             edge zeros via frag masking) + gates + conv_out. One barrier
//             each, 16.3/9.2 KB LDS -> 8 blocks/CU each, free-running.
// Same block->XCD swizzle in both: all tiles of an image live on one XCD ->
// K2's x reads (incl. halo) are same-L2 hits. 32-wide tiles keep output and
// x lines block-exclusive (no write amplification, r11 lesson).
//
// h0 == 0 ⇒ flow/warp/w_ret branch dead; network = conv3x3(24->8) ->
// conv3x3(8->24) -> GRU gates (h2h == b_ret) -> conv1x1(8->12).
// Fragment layouts (HW-verified): A[m=lane&15][k=quad*8+j], C[row=quad*4+reg][col=lane&15].

typedef __fp16   h2f __attribute__((ext_vector_type(2)));   // cvt_pkrtz return type
typedef _Float16 v4h __attribute__((ext_vector_type(4)));
typedef _Float16 v8h __attribute__((ext_vector_type(8)));
typedef float    v4f __attribute__((ext_vector_type(4)));

#define HW 128
#define SPITCH 24        // halfs per staged position: 48 B, 16B-aligned, bank-clean
#define PC1   34         // K1 patch: 34 cols x 10 rows (halo 1)
#define NP1   340
#define NSLOT1 680       // 340 positions x 2 channel-halves

#define WB_HOFF 4608     // half-index of i2h B-frags in ws
#define FLT_OFF 16384    // byte offset of float params in ws
#define X_OFF   65536    // byte offset of x image in ws: (32,128,128,8) f16 = 8.39 MB
#define N_PREP  7828     // 4608 + 3072 halfs, then 148 floats

__global__ __launch_bounds__(256)
void prep(const float* __restrict__ w_in,  const float* __restrict__ b_in,
          const float* __restrict__ w_i2h, const float* __restrict__ b_i2h,
          const float* __restrict__ b_ret, const float* __restrict__ w_out,
          const float* __restrict__ b_out, void* __restrict__ ws)
{
    int idx = blockIdx.x * 256 + threadIdx.x;
    _Float16* wh = (_Float16*)ws;
    float* fw = (float*)((char*)ws + FLT_OFF);
    if (idx < 4608) {                       // conv_in B-frags [s3][g3][lane64][j8]
        int j = idx & 7, r = idx >> 3;
        int lane = r & 63, sg = r >> 6;     // sg = s*3 + g
        int g = sg % 3, s = sg / 3;
        int quad = lane >> 4, n = lane & 15;
        int tap = s * 4 + quad;             // 0..11 (9..11 zero pad)
        float v = (n < 8 && tap < 9) ? w_in[n*216 + (g*8 + j)*9 + tap] : 0.f;
        wh[idx] = (_Float16)v;
    } else if (idx < 7680) {                // i2h B-frags [s3][nt2][lane64][j8]
        int i2 = idx - 4608;
        int j = i2 & 7, r = i2 >> 3;
        int lane = r & 63; r >>= 6;
        int nt = r & 1, s = r >> 1;
        int quad = lane >> 4, n = lane & 15;
        int kk = s * 32 + quad * 8 + j;     // K: tap-major, 8 ch per tap
        int t = kk >> 3, m = kk & 7;        // tap 0..11 (9..11 pad)
        int o = nt * 16 + n;
        float v = (t < 9 && o < 24) ? w_i2h[o*72 + m*9 + t] : 0.f;
        wh[WB_HOFF + i2] = (_Float16)v;
    } else if (idx < N_PREP) {
        int j = idx - 7680;
        float v;
        if (j < 32) {                       // combined gate biases
            int c = j & 7, sel = j >> 3;
            v = (sel==0) ? b_i2h[c]    + b_ret[c]
              : (sel==1) ? b_i2h[8+c]  + b_ret[8+c]
              : (sel==2) ? b_i2h[16+c] : b_ret[16+c];
        } else if (j < 128) v = w_out[j-32];
        else if (j < 140)   v = b_out[j-128];
        else                v = b_in[j-140];   // conv_in bias (K1 epilogue add)
        fw[j] = v;
    }
}

// pack 12 floats -> 12 halfs: one b128 (8) + one b64 (4), both aligned
__device__ __forceinline__ void pack12(_Float16* dst, const float* v)
{
    union { h2f h2[4]; v8h h8; } u;
    union { h2f h2[2]; v4h h4; } w;
#pragma unroll
    for (int k = 0; k < 4; ++k)
        u.h2[k] = __builtin_amdgcn_cvt_pkrtz(v[2*k], v[2*k+1]);
    w.h2[0] = __builtin_amdgcn_cvt_pkrtz(v[8], v[9]);
    w.h2[1] = __builtin_amdgcn_cvt_pkrtz(v[10], v[11]);
    *(v8h*)&dst[0] = u.h8;
    *(v4h*)&dst[8] = w.h4;
}

// shared tile decode: id&7 = XCD; all 64 tiles of an image stay on one XCD.
__device__ __forceinline__ void tile_decode(int id, int& b, int& ty0, int& tx0)
{
    b   = (id & 7) * 4 + (id >> 9);
    int tile = (id >> 3) & 63;
    ty0 = (tile >> 2) << 3;    // 16 y-tiles x 8 rows
    tx0 = (tile & 3) << 5;     // 4 x-tiles x 32 cols
}

__global__ __launch_bounds__(256, 8)
void k1_convin(const float* __restrict__ radar, const float* __restrict__ pred,
               const void* __restrict__ ws, _Float16* __restrict__ xw)
{
    __shared__ __align__(16) _Float16 s_in[NP1 * SPITCH];   // 16320 B

    const _Float16* wh = (const _Float16*)ws;
    const float* fw = (const float*)((const char*)ws + FLT_OFF);

    const int tid  = threadIdx.x;
    const int lane = tid & 63;
    const int wave = tid >> 6;          // 0..3
    const int quad = lane >> 4;
    const int col  = lane & 15;

    int b, ty0, tx0;
    tile_decode(blockIdx.x, b, ty0, tx0);

    // ---- stage halo-1 patch (34x10) as 680 12-channel half-slots ----
    const float* rb = radar + (((size_t)b * 12) << 14);
    const float* pb = pred  + (((size_t)b * 12) << 14);

    const int s0 = tid, s1 = tid + 256, s2 = tid + 512;
    const int p0 = s0 >> 1, p1 = s1 >> 1, p2 = s2 >> 1;
    const bool has2 = (s2 < NSLOT1);    // tid < 168

    const int ly0 = p0 / PC1, lx0 = p0 - PC1 * ly0;
    const int gy0 = ty0 + ly0 - 1, gx0 = tx0 + lx0 - 1;
    const bool in0 = ((unsigned)gy0 < HW) & ((unsigned)gx0 < HW);
    const int off0 = (gy0 << 7) + gx0;
    const float* src0 = (s0 & 1) ? pb : rb;

    const int ly1 = p1 / PC1, lx1 = p1 - PC1 * ly1;
    const int gy1 = ty0 + ly1 - 1, gx1 = tx0 + lx1 - 1;
    const bool in1 = ((unsigned)gy1 < HW) & ((unsigned)gx1 < HW);
    const int off1 = (gy1 << 7) + gx1;
    const float* src1 = (s1 & 1) ? pb : rb;

    const int ly2 = p2 / PC1, lx2 = p2 - PC1 * ly2;
    const int gy2 = ty0 + ly2 - 1, gx2 = tx0 + lx2 - 1;
    const bool in2 = has2 & ((unsigned)gy2 < HW) & ((unsigned)gx2 < HW);
    const int off2 = (gy2 << 7) + gx2;
    const float* src2 = (s2 & 1) ? pb : rb;

    float v0[12], v1[12], v2[12];
#pragma unroll
    for (int c = 0; c < 12; ++c) v0[c] = in0 ? src0[((size_t)c << 14) + off0] : 0.f;
#pragma unroll
    for (int c = 0; c < 12; ++c) v1[c] = in1 ? src1[((size_t)c << 14) + off1] : 0.f;
#pragma unroll
    for (int c = 0; c < 12; ++c) v2[c] = in2 ? src2[((size_t)c << 14) + off2] : 0.f;

    pack12(&s_in[p0 * SPITCH + (s0 & 1) * 12], v0);
    pack12(&s_in[p1 * SPITCH + (s1 & 1) * 12], v1);
    if (has2) pack12(&s_in[p2 * SPITCH + (s2 & 1) * 12], v2);
    __syncthreads();

    // ---- conv_in GEMM: 16 M-tiles over 4 waves, 9 MFMA each ----
    int toffA[3];
#pragma unroll
    for (int s = 0; s < 3; ++s) {
        int t = s * 4 + quad;               // tap carried by this quad
        toffA[s] = (t < 9) ? ((t / 3) * PC1 + (t % 3)) * SPITCH : 0;
    }
    int pbase[4];
#pragma unroll
    for (int t = 0; t < 4; ++t) {
        int p = (wave + 4 * t) * 16 + col;  // output px 0..255
        pbase[t] = ((p >> 5) * PC1 + (p & 31)) * SPITCH;
    }
    v4f accA[4];
#pragma unroll
    for (int t = 0; t < 4; ++t) accA[t] = (v4f){0.f, 0.f, 0.f, 0.f};
#pragma unroll
    for (int s = 0; s < 3; ++s) {
        v8h bg[3];
#pragma unroll
        for (int g = 0; g < 3; ++g)
            bg[g] = *(const v8h*)&wh[((s * 3 + g) * 64 + lane) * 8];
#pragma unroll
        for (int t = 0; t < 4; ++t) {
            int ab = pbase[t] + toffA[s];
#pragma unroll
            for (int g = 0; g < 3; ++g) {
                v8h a = *(const v8h*)&s_in[ab + g * 8];
                accA[t] = __builtin_amdgcn_mfma_f32_16x16x32_f16(a, bg[g], accA[t], 0, 0, 0);
            }
        }
    }

    // ---- store x (+b_in), channel-last f16: x[b][y][x][c] ----
    const float binv = fw[140 + (col & 7)];
    if (col < 8) {
#pragma unroll
        for (int t = 0; t < 4; ++t) {
#pragma unroll
            for (int r = 0; r < 4; ++r) {
                int p = (wave + 4 * t) * 16 + quad * 4 + r;
                int gy = ty0 + (p >> 5), gx = tx0 + (p & 31);
                h2f one = __builtin_amdgcn_cvt_pkrtz(accA[t][r] + binv, 0.f);
                xw[((((size_t)b << 14) + (gy << 7) + gx) << 3) + col] = one[0];
            }
        }
    }
}

__global__ __launch_bounds__(256, 8)
void k2_rest(const _Float16* __restrict__ xw, const void* __restrict__ ws,
             float* __restrict__ out)
{
    __shared__ float s_hc[256 * 9];     // 9216 B

    const _Float16* wh = (const _Float16*)ws;
    const float* fw = (const float*)((const char*)ws + FLT_OFF);

    const int tid  = threadIdx.x;
    const int lane = tid & 63;
    const int wave = tid >> 6;          // 0..3
    const int quad = lane >> 4;
    const int col  = lane & 15;

    int b, ty0, tx0;
    tile_decode(blockIdx.x, b, ty0, tx0);

    // tap offsets per K-step (quad carries tap t = s*4+quad; 9..11 pad, B=0)
    int dys[3], dxs[3];
#pragma unroll
    for (int s = 0; s < 3; ++s) {
        int t = s * 4 + quad;
        dys[s] = (t < 9) ? (t / 3) - 1 : 0;
        dxs[s] = (t < 9) ? (t % 3) - 1 : 0;
    }
    int gyv[4], gxv[4];
#pragma unroll
    for (int t = 0; t < 4; ++t) {
        int p = (wave + 4 * t) * 16 + col;
        gyv[t] = ty0 + (p >> 5);
        gxv[t] = tx0 + (p & 31);
    }
    const _Float16* xb = xw + (((size_t)b << 14) << 3);

    v4f acc0[4], acc1[4];
#pragma unroll
    for (int t = 0; t < 4; ++t) {
        acc0[t] = (v4f){0.f, 0.f, 0.f, 0.f};
        acc1[t] = (v4f){0.f, 0.f, 0.f, 0.f};
    }
#pragma unroll
    for (int s = 0; s < 3; ++s) {
        v8h b0 = *(const v8h*)&wh[WB_HOFF + ((s * 2 + 0) * 64 + lane) * 8];
        v8h b1 = *(const v8h*)&wh[WB_HOFF + ((s * 2 + 1) * 64 + lane) * 8];
#pragma unroll
        for (int t = 0; t < 4; ++t) {
            int sy = gyv[t] + dys[s], sx = gxv[t] + dxs[s];
            bool ok = ((unsigned)sy < HW) & ((unsigned)sx < HW);
            int idx = ok ? ((sy << 7) + sx) : 0;
            v8h a = *(const v8h*)&xb[(size_t)idx << 3];
            if (!ok) a = (v8h)(_Float16)0.f;   // image-edge zero pad of x
            acc0[t] = __builtin_amdgcn_mfma_f32_16x16x32_f16(a, b0, acc0[t], 0, 0, 0);
            acc1[t] = __builtin_amdgcn_mfma_f32_16x16x32_f16(a, b1, acc1[t], 0, 0, 0);
        }
    }

    // ---- gates from C-frags -> s_hc ----
    const int c7 = lane & 7;
    const float g0v = fw[c7], g1v = fw[8 + c7], g2v = fw[16 + c7], g3v = fw[24 + c7];
#pragma unroll
    for (int t = 0; t < 4; ++t) {
        int mt = wave + 4 * t;
#pragma unroll
        for (int r = 0; r < 4; ++r) {
            float iu = __shfl_xor(acc0[t][r], 8, 64);
            if (col < 8) {
                float rr = 1.f / (1.f + __expf(-(acc0[t][r] + g0v)));
                float uu = 1.f / (1.f + __expf(-(iu + g1v)));
                float mm = acc1[t][r] + g2v + rr * g3v;
                mm = (mm >= 0.f) ? mm : 0.2f * mm;
                s_hc[(mt * 16 + quad * 4 + r) * 9 + c7] = (1.f - uu) * mm;
            }
        }
    }
    __syncthreads();

    // ---- conv_out (1x1, 8->12); rows are full 128-B lines ----
    float h[8];
#pragma unroll
    for (int c = 0; c < 8; ++c) h[c] = s_hc[tid * 9 + c];
    const float* wout = fw + 32;
    const float* bout = fw + 128;
    const int oy = tid >> 5, ox = tid & 31;
    float* op = out + (((size_t)b * 12) << 14) + ((ty0 + oy) << 7) + (tx0 + ox);
#pragma unroll
    for (int t = 0; t < 12; ++t) {
        float o = bout[t];
#pragma unroll
        for (int c = 0; c < 8; ++c) o = fmaf(h[c], wout[t * 8 + c], o);
        op[(size_t)t << 14] = o;
    }
}

extern "C" void kernel_launch(void* const* d_in, const int* in_sizes, int n_in,
                              void* d_out, int out_size, void* d_ws, size_t ws_size,
                              hipStream_t stream) {
    (void)in_sizes; (void)n_in; (void)ws_size; (void)out_size;
    const float* radar = (const float*)d_in[0];
    const float* pred  = (const float*)d_in[1];
    const float* w_in  = (const float*)d_in[2];
    const float* b_in  = (const float*)d_in[3];
    const float* w_i2h = (const float*)d_in[4];
    const float* b_i2h = (const float*)d_in[5];
    // d_in[6..12] (flow branch, w_ret) are dead: h0 == 0.
    const float* b_ret = (const float*)d_in[13];
    const float* w_out = (const float*)d_in[14];
    const float* b_out = (const float*)d_in[15];

    _Float16* xw = (_Float16*)((char*)d_ws + X_OFF);

    prep<<<(N_PREP + 255) / 256, 256, 0, stream>>>(w_in, b_in, w_i2h, b_i2h,
                                                   b_ret, w_out, b_out, d_ws);
    k1_convin<<<dim3(2048), dim3(256), 0, stream>>>(radar, pred, d_ws, xw);
    k2_rest<<<dim3(2048), dim3(256), 0, stream>>>(xw, d_ws, (float*)d_out);
}